// Round 1
// baseline (32.453 us; speedup 1.0000x reference)
//
#include <hip/hip_runtime.h>
#include <math.h>

#define GRIDN 128
#define NSAMP 192

__global__ __launch_bounds__(NSAMP) void plenoxel_render_kernel(
    const float* __restrict__ vox_grid,   // [128][128][128][28]
    const float* __restrict__ origins,    // [R][3]
    const float* __restrict__ dirs_in,    // [R][3]
    float* __restrict__ out)              // [R][3]
{
    const int ray  = blockIdx.x;
    const int tid  = threadIdx.x;          // sample index 0..191
    const int lane = tid & 63;
    const int wave = tid >> 6;             // 0..2

    // ---- per-ray setup (redundant per thread, cheap) ----
    const float ox = origins[ray * 3 + 0];
    const float oy = origins[ray * 3 + 1];
    const float oz = origins[ray * 3 + 2];
    float dx = dirs_in[ray * 3 + 0];
    float dy = dirs_in[ray * 3 + 1];
    float dz = dirs_in[ray * 3 + 2];
    const float nrm = sqrtf(dx * dx + dy * dy + dz * dz);
    dx /= nrm; dy /= nrm; dz /= nrm;

    // SH basis: since (dx,dy,dz) is unit, st*cos(phi)=dx, st*sin(phi)=dy, ct=dz
    float sh[9];
    sh[0] = 0.28209479177387814f;                  // Y00
    sh[1] = 0.4886025119029199f * dy;              // C1 * st * sp
    sh[2] = 0.4886025119029199f * dz;              // C1 * ct
    sh[3] = 0.4886025119029199f * dx;              // C1 * st * cp
    sh[4] = 1.0925484305920792f * dx * dy;         // C2H * (st cp)(st sp)
    sh[5] = 1.0925484305920792f * dy * dz;         // C2H * st sp ct
    sh[6] = 0.31539156525252005f * (3.f * dz * dz - 1.f);  // C20*(3ct^2-1)
    sh[7] = 1.0925484305920792f * dx * dz;         // C2H * st cp ct
    sh[8] = 0.5462742152960396f * (dx * dx - dy * dy);     // C2Q*((st cp)^2-(st sp)^2)

    // ---- sample position & trilinear gather ----
    const float t  = (float)tid;   // T_NEAR=0, STEP=1
    const float px = ox + dx * t;
    const float py = oy + dy * t;
    const float pz = oz + dz * t;
    const float fx = floorf(px), fy = floorf(py), fz = floorf(pz);
    const int   ix = (int)fx, iy = (int)fy, iz = (int)fz;
    const float rx = px - fx, ry = py - fy, rz = pz - fz;

    float vox[28];
    #pragma unroll
    for (int c = 0; c < 28; ++c) vox[c] = 0.f;

    #pragma unroll
    for (int cx = 0; cx < 2; ++cx)
    #pragma unroll
    for (int cy = 0; cy < 2; ++cy)
    #pragma unroll
    for (int cz = 0; cz < 2; ++cz) {
        const int X = ix + cx, Y = iy + cy, Z = iz + cz;
        const bool valid = (unsigned)X < GRIDN && (unsigned)Y < GRIDN && (unsigned)Z < GRIDN;
        const float w = (cx ? rx : 1.f - rx) * (cy ? ry : 1.f - ry) * (cz ? rz : 1.f - rz);
        if (valid) {
            const float4* p4 = (const float4*)(vox_grid + (size_t)(((X * GRIDN) + Y) * GRIDN + Z) * 28);
            #pragma unroll
            for (int q = 0; q < 7; ++q) {
                const float4 v = p4[q];
                vox[q * 4 + 0] = fmaf(w, v.x, vox[q * 4 + 0]);
                vox[q * 4 + 1] = fmaf(w, v.y, vox[q * 4 + 1]);
                vox[q * 4 + 2] = fmaf(w, v.z, vox[q * 4 + 2]);
                vox[q * 4 + 3] = fmaf(w, v.w, vox[q * 4 + 3]);
            }
        }
    }

    // ---- sigma, color ----
    const float sigma = fmaxf(vox[0], 0.f);
    float cr = 0.f, cg = 0.f, cb = 0.f;
    #pragma unroll
    for (int k = 0; k < 9; ++k) {
        cr = fmaf(vox[1 + k],  sh[k], cr);
        cg = fmaf(vox[10 + k], sh[k], cg);
        cb = fmaf(vox[19 + k], sh[k], cb);
    }
    cr = fminf(fmaxf(cr, 0.f), 1.f);
    cg = fminf(fmaxf(cg, 0.f), 1.f);
    cb = fminf(fmaxf(cb, 0.f), 1.f);

    // ---- exclusive prefix-sum of sigma over the 192 samples ----
    float incl = sigma;
    #pragma unroll
    for (int d = 1; d < 64; d <<= 1) {
        const float v = __shfl_up(incl, d, 64);
        if (lane >= d) incl += v;
    }

    __shared__ float wtot[3];
    __shared__ float redr[3], redg[3], redb[3];
    if (lane == 63) wtot[wave] = incl;
    __syncthreads();

    float off = 0.f;
    for (int wv = 0; wv < wave; ++wv) off += wtot[wv];   // wave-uniform
    const float excl  = off + (incl - sigma);
    const float trans = expf(-excl);
    const float alpha = 1.f - expf(-sigma);
    const float wt    = trans * alpha;

    float r = wt * cr, g = wt * cg, b = wt * cb;
    #pragma unroll
    for (int d = 32; d >= 1; d >>= 1) {
        r += __shfl_xor(r, d, 64);
        g += __shfl_xor(g, d, 64);
        b += __shfl_xor(b, d, 64);
    }
    if (lane == 0) { redr[wave] = r; redg[wave] = g; redb[wave] = b; }
    __syncthreads();

    if (tid == 0) {
        const float tfinal = expf(-(wtot[0] + wtot[1] + wtot[2]));
        out[ray * 3 + 0] = redr[0] + redr[1] + redr[2] + tfinal;
        out[ray * 3 + 1] = redg[0] + redg[1] + redg[2] + tfinal;
        out[ray * 3 + 2] = redb[0] + redb[1] + redb[2] + tfinal;
    }
}

extern "C" void kernel_launch(void* const* d_in, const int* in_sizes, int n_in,
                              void* d_out, int out_size, void* d_ws, size_t ws_size,
                              hipStream_t stream) {
    const float* vox_grid = (const float*)d_in[0];
    const float* origins  = (const float*)d_in[1];
    const float* dirs     = (const float*)d_in[2];
    float*       out      = (float*)d_out;
    const int R = in_sizes[1] / 3;   // 2048 rays
    plenoxel_render_kernel<<<R, NSAMP, 0, stream>>>(vox_grid, origins, dirs, out);
}